// Round 13
// baseline (155.795 us; speedup 1.0000x reference)
//
#include <hip/hip_runtime.h>

// SparseMCFModel — output `flow` depends ONLY on demands, edge_row, edge_col.
// w_e = 1/deg(row_e) exactly (softmax over identical logits per segment) -> the
// GAT/GRU/decoder pipeline is dead code. Since w depends on row only:
//   flow_j[e] = V_j[row_e],
//   V_1[v] = relu(d[v])/deg[v],
//   V_j[v] = (relu(d[v]) + sum_{e:col=v} V_{j-1}[row_e]) / deg[v],  j=2..10
//   out[e] = V_10[row_e].
//
// r12 lesson: WRITE_SIZE == per-op write-through of agent-scope ops; build's
// 400K COLLIDING fetch_adds (~10-way/address) are ~40us of the 70us kernel.
// r13: ATOMIC-FREE build. Each block histograms its contiguous 1563-edge
// chunk in an 80KB LDS array (rows pass -> degT[b][*]; cols pass -> inhT[b][*]
// with per-edge local index kept in registers). Owners reduce the 128-block
// tables (coalesced coherent reads), emit clamped per-block prefix bytes
// pre[b][v], and placement computes gidx = pre[bx][c]+lidx deterministically.
// Only global atomic left: the (expected-0) overflow counter.
// Barrier: zero-cache-op relaxed monotone counter (validated r6-r12).

#define N_NODES 20000
#define N_EDGES 200000
#define FLOW_ITERS 10
#define NBLK 128
#define NTHR 512
#define EPB 1563                           // edges per block (128*1563=200064)
#define EPT ((EPB + NTHR - 1) / NTHR)      // 4
#define NPB 157                            // nodes per block (128*157 = 20096)
#define CAP 24                             // padded in-edge slots per node
#define SLOTS (NBLK * NTHR)                // slot space: bx*NTHR + tx
#define NWORD (N_NODES / 2)                // 10000 packed u16-pair words
#define NPADV 20224                        // padded v-dim for pre table
#define OFL_MAX 4096
#define NP1 (N_NODES + 1)

__device__ __forceinline__ float ld_coh(const float* p) {
    return __hip_atomic_load(p, __ATOMIC_RELAXED, __HIP_MEMORY_SCOPE_AGENT);
}
__device__ __forceinline__ int ld_coh_i(const int* p) {
    return __hip_atomic_load(p, __ATOMIC_RELAXED, __HIP_MEMORY_SCOPE_AGENT);
}
__device__ __forceinline__ void st_coh(float* p, float v) {
    __hip_atomic_store(p, v, __ATOMIC_RELAXED, __HIP_MEMORY_SCOPE_AGENT);
}
__device__ __forceinline__ void st_coh_i(int* p, int v) {
    __hip_atomic_store(p, v, __ATOMIC_RELAXED, __HIP_MEMORY_SCOPE_AGENT);
}
__device__ __forceinline__ void st_coh_u(unsigned* p, unsigned v) {
    __hip_atomic_store(p, v, __ATOMIC_RELAXED, __HIP_MEMORY_SCOPE_AGENT);
}

// Zero-cache-op monotone barrier (validated r6-r12): __syncthreads drains
// vmcnt per wave before s_barrier -> coherent-point writes globally visible
// before the relaxed arrive; post-barrier cross-block reads use coherent ops
// or touch lines never cached stale.
__device__ __forceinline__ void gbar(int* cnt, int target) {
    __syncthreads();
    if (threadIdx.x == 0) {
        __hip_atomic_fetch_add(cnt, 1, __ATOMIC_RELAXED, __HIP_MEMORY_SCOPE_AGENT);
        while (__hip_atomic_load(cnt, __ATOMIC_RELAXED, __HIP_MEMORY_SCOPE_AGENT) < target)
            __builtin_amdgcn_s_sleep(2);
    }
    __syncthreads();
}

__device__ __forceinline__ int half16(int w, int hi) {
    return hi ? ((w >> 16) & 0xFFFF) : (w & 0xFFFF);
}

__global__ __launch_bounds__(NTHR)
void mcf_fused(const float* __restrict__ demands,
               const int* __restrict__ edge_row,
               const int* __restrict__ edge_col,
               float* __restrict__ out,
               int* __restrict__ degT,      // [NBLK*NWORD] packed u16 pairs
               int* __restrict__ inhT,      // [NBLK*NWORD] packed u16 pairs
               unsigned* __restrict__ pre32,// [32*NPADV]: byte (b&3) of word
                                            //   [(b>>2)*NPADV + v]
               float* __restrict__ V0,      // [N+1] zeroed by memset (sentinel)
               float* __restrict__ V1b,     // [N+1] zeroed by memset (sentinel)
               int* __restrict__ pcsc,      // [SLOTS*CAP], [slot(v)*CAP + k]
               int* __restrict__ ofl_cnt,   // [1] zeroed by memset
               int* __restrict__ ofl_v,     // [OFL_MAX]
               int* __restrict__ ofl_row,   // [OFL_MAX]
               int* __restrict__ barcnt)    // [1] zeroed by memset
{
    const int tx = threadIdx.x, bx = blockIdx.x;
    int bar = 0;

    __shared__ int ldsH[N_NODES];   // 80 KB block-local histogram

    // ---- Pass A: row histogram of this block's contiguous edge chunk ----
    int rowr[EPT], colr[EPT], lidx[EPT];
    for (int i = tx; i < N_NODES; i += NTHR) ldsH[i] = 0;
    __syncthreads();
    #pragma unroll
    for (int i = 0; i < EPT; ++i) {
        int local = i * NTHR + tx, e = bx * EPB + local;
        rowr[i] = -1;
        if (local < EPB && e < N_EDGES) {
            rowr[i] = edge_row[e];
            colr[i] = edge_col[e];
            atomicAdd(&ldsH[rowr[i]], 1);       // LDS atomic, sparse
        }
    }
    __syncthreads();
    for (int wi = tx; wi < NWORD; wi += NTHR)
        st_coh_i(&degT[bx * NWORD + wi], ldsH[2 * wi] | (ldsH[2 * wi + 1] << 16));
    __syncthreads();

    // ---- Pass B: col histogram; LDS fetch_add return = local index ----
    for (int i = tx; i < N_NODES; i += NTHR) ldsH[i] = 0;
    __syncthreads();
    #pragma unroll
    for (int i = 0; i < EPT; ++i)
        if (rowr[i] >= 0) lidx[i] = atomicAdd(&ldsH[colr[i]], 1);
    __syncthreads();
    for (int wi = tx; wi < NWORD; wi += NTHR)
        st_coh_i(&inhT[bx * NWORD + wi], ldsH[2 * wi] | (ldsH[2 * wi + 1] << 16));
    gbar(barcnt, NBLK * (++bar));

    // ---- Owner reduction: deg sum, inh prefix -> pre bytes, publish V_1 ----
    const int v = bx * NPB + tx;
    const bool active = (tx < NPB) && (v < N_NODES);
    float dposv = 0.0f, invd = 0.0f;
    int   cnt = 0, ocnt = 0;
    int   er[CAP];
    if (active) {
        const int wv = v >> 1, hv = v & 1;
        int sdeg = 0;
        #pragma unroll 1
        for (int g = 0; g < NBLK / 8; ++g) {     // batches of 8 for ILP
            int w0 = ld_coh_i(&degT[(g*8+0) * NWORD + wv]);
            int w1 = ld_coh_i(&degT[(g*8+1) * NWORD + wv]);
            int w2 = ld_coh_i(&degT[(g*8+2) * NWORD + wv]);
            int w3 = ld_coh_i(&degT[(g*8+3) * NWORD + wv]);
            int w4 = ld_coh_i(&degT[(g*8+4) * NWORD + wv]);
            int w5 = ld_coh_i(&degT[(g*8+5) * NWORD + wv]);
            int w6 = ld_coh_i(&degT[(g*8+6) * NWORD + wv]);
            int w7 = ld_coh_i(&degT[(g*8+7) * NWORD + wv]);
            sdeg += half16(w0,hv)+half16(w1,hv)+half16(w2,hv)+half16(w3,hv)
                  + half16(w4,hv)+half16(w5,hv)+half16(w6,hv)+half16(w7,hv);
        }
        int acc = 0;
        #pragma unroll 1
        for (int g = 0; g < NBLK / 8; ++g) {
            int w[8];
            #pragma unroll
            for (int q = 0; q < 8; ++q)
                w[q] = ld_coh_i(&inhT[(g*8+q) * NWORD + wv]);
            unsigned pw0 = 0, pw1 = 0;
            #pragma unroll
            for (int q = 0; q < 4; ++q) {
                pw0 |= (unsigned)min(acc, 255) << (8*q);
                acc += half16(w[q], hv);
            }
            #pragma unroll
            for (int q = 0; q < 4; ++q) {
                pw1 |= (unsigned)min(acc, 255) << (8*q);
                acc += half16(w[4+q], hv);
            }
            st_coh_u(&pre32[(g*2+0) * NPADV + v], pw0);
            st_coh_u(&pre32[(g*2+1) * NPADV + v], pw1);
        }
        cnt   = min(acc, CAP);
        dposv = fmaxf(demands[v], 0.0f);
        invd  = (sdeg > 0) ? (1.0f / (float)sdeg) : 0.0f;  // V[v] unread if deg==0
        st_coh(&V0[v], dposv * invd);                      // publish V_1
    }
    gbar(barcnt, NBLK * (++bar));

    // ---- Placement: gidx = pre[bx][c] + lidx (deterministic, atomic-free) ----
    #pragma unroll
    for (int i = 0; i < EPT; ++i) {
        if (rowr[i] >= 0) {
            int c = colr[i];
            unsigned pw = pre32[(bx >> 2) * NPADV + c];   // plain: fresh lines
            int pre = (pw >> (8 * (bx & 3))) & 0xFF;
            int gidx = pre + lidx[i];
            if (gidx < CAP) {
                int slot = (c / NPB) * NTHR + (c % NPB);
                st_coh_i(&pcsc[slot * CAP + gidx], rowr[i]);
            } else {
                int o = __hip_atomic_fetch_add(ofl_cnt, 1,
                                               __ATOMIC_RELAXED, __HIP_MEMORY_SCOPE_AGENT);
                if (o < OFL_MAX) { st_coh_i(&ofl_v[o], c); st_coh_i(&ofl_row[o], rowr[i]); }
            }
        }
    }
    gbar(barcnt, NBLK * (++bar));

    // ---- Owner setup: register-cache in-edge rows (coalesced-ish reads) ----
    if (active) {
        ocnt = ld_coh_i(ofl_cnt);                        // expected 0
        const int slot = bx * NTHR + tx;                 // == slot(v)
        #pragma unroll
        for (int k = 0; k < CAP; ++k) {
            int r = pcsc[slot * CAP + k];     // plain; lines never cached stale
            er[k] = (k < cnt) ? r : N_NODES;  // dummy -> zero sentinel
        }
    }

    // ---- 9 iterations: CAP independent random coherent gathers per node ----
    #pragma unroll 1
    for (int j = 2; j <= FLOW_ITERS; ++j) {
        const float* Vp = (j & 1) ? V1b : V0;   // j even: read V0, write V1b
        float*       Vn = (j & 1) ? V0 : V1b;
        if (active) {
            float sk[CAP];
            #pragma unroll
            for (int s = 0; s < CAP; ++s) sk[s] = ld_coh(&Vp[er[s]]);
            float acc = dposv;
            #pragma unroll
            for (int s = 0; s < CAP; ++s) acc += sk[s];
            if (ocnt > 0) {                     // exactness fallback, ~never
                for (int o = 0; o < ocnt && o < OFL_MAX; ++o)
                    if (ld_coh_i(&ofl_v[o]) == v)
                        acc += ld_coh(&Vp[ld_coh_i(&ofl_row[o])]);
            }
            st_coh(&Vn[v], acc * invd);         // coalesced publish
        }
        gbar(barcnt, NBLK * (++bar));
    }

    // ---- out[e] = V_10[row_e]  (j=10 wrote V1b); coalesced stores ----
    #pragma unroll
    for (int i = 0; i < EPT; ++i) {
        int local = i * NTHR + tx, e = bx * EPB + local;
        if (local < EPB && e < N_EDGES) out[e] = ld_coh(&V1b[rowr[i]]);
    }
}

extern "C" void kernel_launch(void* const* d_in, const int* in_sizes, int n_in,
                              void* d_out, int out_size, void* d_ws, size_t ws_size,
                              hipStream_t stream) {
    const float* demands  = (const float*)d_in[1];
    const int*   edge_row = (const int*)d_in[2];
    const int*   edge_col = (const int*)d_in[3];
    float*       out      = (float*)d_out;

    char* ws = (char*)d_ws;
    auto take = [&](size_t bytes) {
        void* p = (void*)ws;
        ws += (bytes + 127) & ~size_t(127);
        return p;
    };
    // ---- zero zone (one 0x00 memset): V sentinels + counters ----
    char* zone0 = ws;
    float*    V0      = (float*)   take(NP1 * 4);
    float*    V1b     = (float*)   take(NP1 * 4);
    int*      ofl_cnt = (int*)     take(4);
    int*      barcnt  = (int*)     take(4);
    size_t zone0_bytes = (size_t)(ws - zone0);
    // ---- uninitialized zone (fully overwritten before any read) ----
    int*      degT    = (int*)     take((size_t)NBLK * NWORD * 4);
    int*      inhT    = (int*)     take((size_t)NBLK * NWORD * 4);
    unsigned* pre32   = (unsigned*)take((size_t)32 * NPADV * 4);
    int*      pcsc    = (int*)     take((size_t)SLOTS * CAP * 4);
    int*      ofl_v   = (int*)     take(OFL_MAX * 4);
    int*      ofl_row = (int*)     take(OFL_MAX * 4);

    hipMemsetAsync(zone0, 0x00, zone0_bytes, stream);
    mcf_fused<<<NBLK, NTHR, 0, stream>>>(demands, edge_row, edge_col, out,
                                         degT, inhT, pre32, V0, V1b, pcsc,
                                         ofl_cnt, ofl_v, ofl_row, barcnt);
}

// Round 14
// 122.147 us; speedup vs baseline: 1.2755x; 1.2755x over previous
//
#include <hip/hip_runtime.h>

// SparseMCFModel — output `flow` depends ONLY on demands, edge_row, edge_col.
// w_e = 1/deg(row_e) exactly (softmax over identical logits per segment) -> the
// GAT/GRU/decoder pipeline is dead code. Since w depends on row only:
//   flow_j[e] = V_j[row_e],
//   V_1[v] = relu(d[v])/deg[v],
//   V_j[v] = (relu(d[v]) + sum_{e:col=v} V_{j-1}[row_e]) / deg[v],  j=2..10
//   out[e] = V_10[row_e].
//
// r13 lesson: global colliding atomics are CHEAP (table-reduction build that
// removed them regressed via 5.1M coherent table reads). r12 (70us) budget:
// barriers ~2.5us each (128 serialized same-line arrivals), iterations on only
// 157/512 threads with 14 dummy loads per node. r14, on the r12 skeleton:
//  (1) distributed-arrival barrier: 8 padded counters, 16 RMWs each in
//      parallel; pollers sum all 8 (ILP, one round-trip)
//  (2) 3 roles x 8 slots per node (471/512 threads), loads predicated on
//      k<cnt (-58% gather transactions), LDS partial sums, role-0 publishes
//  (3) int4 edge loads / float4 out stores (contiguous per-block chunks)

#define N_NODES 20000
#define N_EDGES 200000
#define FLOW_ITERS 10
#define NBLK 128
#define NTHR 512
#define NPB 157                            // nodes per block (128*157 = 20096)
#define CAP 24                             // padded in-edge slots per node
#define NQUAD 50000                        // N_EDGES/4 int4 quads
#define QPB 391                            // quads per block (391*128 = 50048)
#define OFL_MAX 4096
#define NP1 (N_NODES + 1)

__device__ __forceinline__ float ld_coh(const float* p) {
    return __hip_atomic_load(p, __ATOMIC_RELAXED, __HIP_MEMORY_SCOPE_AGENT);
}
__device__ __forceinline__ int ld_coh_i(const int* p) {
    return __hip_atomic_load(p, __ATOMIC_RELAXED, __HIP_MEMORY_SCOPE_AGENT);
}
__device__ __forceinline__ void st_coh(float* p, float v) {
    __hip_atomic_store(p, v, __ATOMIC_RELAXED, __HIP_MEMORY_SCOPE_AGENT);
}
__device__ __forceinline__ void st_coh_i(int* p, int v) {
    __hip_atomic_store(p, v, __ATOMIC_RELAXED, __HIP_MEMORY_SCOPE_AGENT);
}

// Distributed-arrival zero-cache-op barrier (soundness as r6-r13: syncthreads
// drains vmcnt before s_barrier; cross-block mutable data only via coherent-
// point ops). Arrivals spread over 8 padded lines (16 serialized RMWs each,
// groups in parallel); pollers sum all 8 with independent loads.
__device__ __forceinline__ void gbar(int* grp, int ord) {
    __syncthreads();
    if (threadIdx.x == 0) {
        __hip_atomic_fetch_add(&grp[(blockIdx.x & 7) * 32], 1,
                               __ATOMIC_RELAXED, __HIP_MEMORY_SCOPE_AGENT);
        const int target = NBLK * ord;
        for (;;) {
            int s = 0;
            #pragma unroll
            for (int g = 0; g < 8; ++g)
                s += __hip_atomic_load(&grp[g * 32], __ATOMIC_RELAXED,
                                       __HIP_MEMORY_SCOPE_AGENT);
            if (s >= target) break;
            __builtin_amdgcn_s_sleep(1);
        }
    }
    __syncthreads();
}

__global__ __launch_bounds__(NTHR)
void mcf_fused(const float* __restrict__ demands,
               const int* __restrict__ edge_row,   // int4-aligned
               const int* __restrict__ edge_col,
               float* __restrict__ out,
               int* __restrict__ deg,       // [N]   zeroed by memset
               int* __restrict__ fill,      // [N]   zeroed by memset
               float* __restrict__ V0,      // [N+1] zeroed by memset
               float* __restrict__ V1b,     // [N+1] zeroed by memset
               int* __restrict__ pcsc,      // [N*CAP], [v*CAP + k]
               int* __restrict__ ofl_cnt,   // [1]   zeroed by memset
               int* __restrict__ ofl_v,     // [OFL_MAX]
               int* __restrict__ ofl_row,   // [OFL_MAX]
               int* __restrict__ grp)       // [8*32] zeroed by memset
{
    const int tx = threadIdx.x, bx = blockIdx.x;
    int bar = 0;

    __shared__ float part[NTHR];

    // ---- Build: int4 edge loads, deg/fill atomics, column-local placement ----
    const int m = bx * QPB + tx;                  // this thread's quad
    const bool bld = (tx < QPB) && (m < NQUAD);
    int4 r4 = {0, 0, 0, 0}, c4 = {0, 0, 0, 0};
    if (bld) {
        r4 = ((const int4*)edge_row)[m];
        c4 = ((const int4*)edge_col)[m];
        int rr[4] = {r4.x, r4.y, r4.z, r4.w};
        int cc[4] = {c4.x, c4.y, c4.z, c4.w};
        #pragma unroll
        for (int i = 0; i < 4; ++i) {
            __hip_atomic_fetch_add(&deg[rr[i]], 1, __ATOMIC_RELAXED, __HIP_MEMORY_SCOPE_AGENT);
            int idx = __hip_atomic_fetch_add(&fill[cc[i]], 1,
                                             __ATOMIC_RELAXED, __HIP_MEMORY_SCOPE_AGENT);
            if (idx < CAP) {
                st_coh_i(&pcsc[cc[i] * CAP + idx], rr[i]);   // 2-line-local
            } else {
                int o = __hip_atomic_fetch_add(ofl_cnt, 1,
                                               __ATOMIC_RELAXED, __HIP_MEMORY_SCOPE_AGENT);
                if (o < OFL_MAX) { st_coh_i(&ofl_v[o], cc[i]); st_coh_i(&ofl_row[o], rr[i]); }
            }
        }
    }
    gbar(grp, ++bar);

    // ---- Role setup: g = node-in-block, q = role (slots q*8..q*8+7) ----
    const int g = tx / 3, q = tx - 3 * g;
    const int v = bx * NPB + g;
    const bool active = (g < NPB) && (v < N_NODES);
    float dposv = 0.0f, invd = 0.0f;
    int   cnt = 0, ocnt = 0;
    int   er[8];
    if (active) {
        cnt = min(ld_coh_i(&fill[v]), CAP);
        // two int4 plain loads; 32B-aligned (v*96 + q*32); lines fresh (st_coh-
        // written, never read pre-barrier) -> cannot be cached stale
        const int4* pb = (const int4*)&pcsc[v * CAP + q * 8];
        int4 a = pb[0], b = pb[1];
        er[0]=a.x; er[1]=a.y; er[2]=a.z; er[3]=a.w;
        er[4]=b.x; er[5]=b.y; er[6]=b.z; er[7]=b.w;
        if (q == 0) {
            dposv  = fmaxf(demands[v], 0.0f);
            int dv = ld_coh_i(&deg[v]);
            invd   = (dv > 0) ? (1.0f / (float)dv) : 0.0f;  // V[v] unread if deg==0
            ocnt   = ld_coh_i(ofl_cnt);                     // expected 0
            st_coh(&V0[v], dposv * invd);                   // publish V_1
        }
    }
    gbar(grp, ++bar);

    // ---- 9 iterations: predicated 8-slot role gathers + LDS 3-way reduce ----
    #pragma unroll 1
    for (int j = 2; j <= FLOW_ITERS; ++j) {
        const float* Vp = (j & 1) ? V1b : V0;   // j even: read V0, write V1b
        float*       Vn = (j & 1) ? V0 : V1b;
        if (active) {
            float p = 0.0f;
            #pragma unroll
            for (int s = 0; s < 8; ++s)
                if (q * 8 + s < cnt) p += ld_coh(&Vp[er[s]]);   // predicated
            part[tx] = p;
        }
        __syncthreads();
        if (active && q == 0) {
            float acc = dposv + part[tx] + part[tx + 1] + part[tx + 2];
            if (ocnt > 0) {                     // exactness fallback, ~never
                for (int o = 0; o < ocnt && o < OFL_MAX; ++o)
                    if (ld_coh_i(&ofl_v[o]) == v)
                        acc += ld_coh(&Vp[ld_coh_i(&ofl_row[o])]);
            }
            st_coh(&Vn[v], acc * invd);         // publish V_j
        }
        gbar(grp, ++bar);
    }

    // ---- out[e] = V_10[row_e] (j=10 wrote V1b); float4 stores ----
    if (bld) {
        float4 o4;
        o4.x = ld_coh(&V1b[r4.x]);
        o4.y = ld_coh(&V1b[r4.y]);
        o4.z = ld_coh(&V1b[r4.z]);
        o4.w = ld_coh(&V1b[r4.w]);
        ((float4*)out)[m] = o4;
    }
}

extern "C" void kernel_launch(void* const* d_in, const int* in_sizes, int n_in,
                              void* d_out, int out_size, void* d_ws, size_t ws_size,
                              hipStream_t stream) {
    const float* demands  = (const float*)d_in[1];
    const int*   edge_row = (const int*)d_in[2];
    const int*   edge_col = (const int*)d_in[3];
    float*       out      = (float*)d_out;

    char* ws = (char*)d_ws;
    auto take = [&](size_t bytes) {
        void* p = (void*)ws;
        ws += (bytes + 127) & ~size_t(127);
        return p;
    };
    // ---- zero zone (one 0x00 memset) ----
    char* zone0 = ws;
    int*   deg     = (int*)  take(N_NODES * 4);
    int*   fill    = (int*)  take(N_NODES * 4);
    float* V0      = (float*)take(NP1 * 4);
    float* V1b     = (float*)take(NP1 * 4);
    int*   ofl_cnt = (int*)  take(4);
    int*   grp     = (int*)  take(8 * 32 * 4);
    size_t zone0_bytes = (size_t)(ws - zone0);
    // ---- uninitialized zone ----
    int*   pcsc    = (int*)  take((size_t)N_NODES * CAP * 4);
    int*   ofl_v   = (int*)  take(OFL_MAX * 4);
    int*   ofl_row = (int*)  take(OFL_MAX * 4);

    hipMemsetAsync(zone0, 0x00, zone0_bytes, stream);
    mcf_fused<<<NBLK, NTHR, 0, stream>>>(demands, edge_row, edge_col, out,
                                         deg, fill, V0, V1b, pcsc,
                                         ofl_cnt, ofl_v, ofl_row, grp);
}